// Round 1
// baseline (1298.134 us; speedup 1.0000x reference)
//
#include <hip/hip_runtime.h>
#include <stdint.h>

#define N_NODES 100000
#define N_EDGES 1600000
#define F 128

// ---------------- preprocessing kernels ----------------

__global__ void k_fill_deg(float* deg, int n) {
    int i = blockIdx.x * blockDim.x + threadIdx.x;
    if (i < n) deg[i] = 1.0f;  // implicit self-loop weight
}

__global__ void k_zero_int(int* p, int n) {
    int i = blockIdx.x * blockDim.x + threadIdx.x;
    if (i < n) p[i] = 0;
}

__global__ void k_deg_accum(const int* __restrict__ ei, const float* __restrict__ w,
                            float* deg, int e) {
    int i = blockIdx.x * blockDim.x + threadIdx.x;
    if (i < e) {
        int d = ei[N_EDGES + i];
        atomicAdd(&deg[d], w[i]);
    }
}

__global__ void k_dinv(float* deg, int n) {
    int i = blockIdx.x * blockDim.x + threadIdx.x;
    if (i < n) deg[i] = rsqrtf(deg[i]);
}

__global__ void k_enorm_hist(const int* __restrict__ ei, const float* __restrict__ w,
                             const float* __restrict__ dinv, float* enorm, int* cnt, int e) {
    int i = blockIdx.x * blockDim.x + threadIdx.x;
    if (i < e) {
        int s = ei[i];
        int d = ei[N_EDGES + i];
        enorm[i] = dinv[s] * w[i] * dinv[d];
        atomicAdd(&cnt[d], 1);
    }
}

// single-block exclusive scan of cnt (in pos) -> row; pos becomes scatter cursor
__launch_bounds__(1024)
__global__ void k_scan(int* cnt_pos, int* row, int n) {
    __shared__ int lsum[1024];
    int tid = threadIdx.x;
    int chunk = (n + 1023) >> 10;
    int lo = tid * chunk;
    int hi = lo + chunk;
    if (lo > n) lo = n;
    if (hi > n) hi = n;
    int s = 0;
    for (int i = lo; i < hi; i++) s += cnt_pos[i];
    lsum[tid] = s;
    __syncthreads();
    for (int off = 1; off < 1024; off <<= 1) {
        int v = (tid >= off) ? lsum[tid - off] : 0;
        __syncthreads();
        lsum[tid] += v;
        __syncthreads();
    }
    int run = (tid == 0) ? 0 : lsum[tid - 1];
    for (int i = lo; i < hi; i++) {
        int c = cnt_pos[i];
        row[i] = run;
        cnt_pos[i] = run;  // pos = row copy for scatter
        run += c;
    }
    if (tid == 1023) row[n] = lsum[1023];
}

__global__ void k_scatter(const int* __restrict__ ei, const float* __restrict__ enorm,
                          int* pos, int* csrc, float* cw, int e) {
    int i = blockIdx.x * blockDim.x + threadIdx.x;
    if (i < e) {
        int d = ei[N_EDGES + i];
        int p = atomicAdd(&pos[d], 1);
        csrc[p] = ei[i];
        cw[p] = enorm[i];
    }
}

// ---------------- fp32 GEMM: H[nrows x 128] = X[nrows x 128] @ W[128 x 128] ----------------

#define GKT 16
#define GS 132  // padded LDS stride

__launch_bounds__(256, 4)
__global__ void k_gemm(const float* __restrict__ X, const float* __restrict__ W,
                       float* __restrict__ H, int nrows) {
    __shared__ float As[GKT * GS];  // A^T tile: As[kk][r]
    __shared__ float Bs[GKT * GS];  // B tile:  Bs[kk][c]
    int tid = threadIdx.x;
    int tx = tid & 15, ty = tid >> 4;
    int r0 = blockIdx.x * 128;
    float acc[8][8];
#pragma unroll
    for (int i = 0; i < 8; i++)
#pragma unroll
        for (int j = 0; j < 8; j++) acc[i][j] = 0.f;

    for (int k0 = 0; k0 < F; k0 += GKT) {
        // stage A (128 rows x 16 k), transposed into LDS
#pragma unroll
        for (int it = 0; it < 2; it++) {
            int f = tid + it * 256;          // 512 float4s
            int r = f >> 2;
            int kc = (f & 3) * 4;
            float4 v = make_float4(0.f, 0.f, 0.f, 0.f);
            if (r0 + r < nrows)
                v = *(const float4*)&X[(size_t)(r0 + r) * F + k0 + kc];
            As[(kc + 0) * GS + r] = v.x;
            As[(kc + 1) * GS + r] = v.y;
            As[(kc + 2) * GS + r] = v.z;
            As[(kc + 3) * GS + r] = v.w;
        }
        // stage B (16 k x 128 cols)
#pragma unroll
        for (int it = 0; it < 2; it++) {
            int f = tid + it * 256;
            int kk = f >> 5;
            int cc = (f & 31) * 4;
            *(float4*)&Bs[kk * GS + cc] = *(const float4*)&W[(size_t)(k0 + kk) * F + cc];
        }
        __syncthreads();
#pragma unroll
        for (int kk = 0; kk < GKT; kk++) {
            float a[8], b[8];
            *(float4*)&a[0] = *(const float4*)&As[kk * GS + ty * 8];
            *(float4*)&a[4] = *(const float4*)&As[kk * GS + ty * 8 + 4];
            *(float4*)&b[0] = *(const float4*)&Bs[kk * GS + tx * 8];
            *(float4*)&b[4] = *(const float4*)&Bs[kk * GS + tx * 8 + 4];
#pragma unroll
            for (int i = 0; i < 8; i++)
#pragma unroll
                for (int j = 0; j < 8; j++)
                    acc[i][j] = fmaf(a[i], b[j], acc[i][j]);
        }
        __syncthreads();
    }
#pragma unroll
    for (int i = 0; i < 8; i++) {
        int r = r0 + ty * 8 + i;
        if (r < nrows) {
            *(float4*)&H[(size_t)r * F + tx * 8] = *(float4*)&acc[i][0];
            *(float4*)&H[(size_t)r * F + tx * 8 + 4] = *(float4*)&acc[i][4];
        }
    }
}

// ---------------- aggregation: out[i] = sum_e w_e * H[src_e] + self*H[i] + b ----------------
// one wave (64 lanes) per node, 2 floats per lane

__launch_bounds__(256)
__global__ void k_agg(const float* __restrict__ H, const int* __restrict__ row,
                      const int* __restrict__ csrc, const float* __restrict__ cw,
                      const float* __restrict__ dinv, const float* __restrict__ bias,
                      float* __restrict__ out, int n, int relu) {
    int node = blockIdx.x * 4 + (threadIdx.x >> 6);
    int lane = threadIdx.x & 63;
    if (node >= n) return;
    float di = dinv[node];
    float sn = di * di;
    float2 h = *(const float2*)&H[(size_t)node * F + lane * 2];
    float2 acc;
    acc.x = sn * h.x;
    acc.y = sn * h.y;
    int beg = row[node], end = row[node + 1];
    for (int j = beg; j < end; j++) {
        int s = csrc[j];
        float w = cw[j];
        float2 v = *(const float2*)&H[(size_t)s * F + lane * 2];
        acc.x = fmaf(w, v.x, acc.x);
        acc.y = fmaf(w, v.y, acc.y);
    }
    float2 b = *(const float2*)&bias[lane * 2];
    acc.x += b.x;
    acc.y += b.y;
    if (relu) {
        acc.x = fmaxf(acc.x, 0.f);
        acc.y = fmaxf(acc.y, 0.f);
    }
    *(float2*)&out[(size_t)node * F + lane * 2] = acc;
}

// ---------------- final layer: per-node dot with W_fin, then scalar aggregation ----------------

__launch_bounds__(256)
__global__ void k_dot(const float* __restrict__ H, const float* __restrict__ Wf,
                      float* __restrict__ s, int n) {
    int node = blockIdx.x * 4 + (threadIdx.x >> 6);
    int lane = threadIdx.x & 63;
    if (node >= n) return;
    float2 h = *(const float2*)&H[(size_t)node * F + lane * 2];
    float2 w = *(const float2*)&Wf[lane * 2];
    float p = h.x * w.x + h.y * w.y;
    for (int off = 32; off; off >>= 1) p += __shfl_down(p, off, 64);
    if (lane == 0) s[node] = p;
}

__global__ void k_aggs(const float* __restrict__ s, const int* __restrict__ row,
                       const int* __restrict__ csrc, const float* __restrict__ cw,
                       const float* __restrict__ dinv, const float* __restrict__ bf,
                       float* __restrict__ out, int n) {
    int i = blockIdx.x * blockDim.x + threadIdx.x;
    if (i >= n) return;
    float di = dinv[i];
    float acc = di * di * s[i];
    int beg = row[i], end = row[i + 1];
    for (int j = beg; j < end; j++) acc = fmaf(cw[j], s[csrc[j]], acc);
    out[i] = acc + bf[0];
}

// ---------------- host launch ----------------

extern "C" void kernel_launch(void* const* d_in, const int* in_sizes, int n_in,
                              void* d_out, int out_size, void* d_ws, size_t ws_size,
                              hipStream_t stream) {
    const float* x    = (const float*)d_in[0];
    const int*   ei   = (const int*)d_in[1];   // int32 per JAX default (x64 disabled)
    const float* ew   = (const float*)d_in[2];
    const float* Win  = (const float*)d_in[3];
    const float* bin  = (const float*)d_in[4];
    const float* Wmid = (const float*)d_in[5];
    const float* bmid = (const float*)d_in[6];
    const float* Wfin = (const float*)d_in[7];
    const float* bfin = (const float*)d_in[8];
    float* out = (float*)d_out;

    char* ws = (char*)d_ws;
    size_t off = 0;
    auto alloc = [&](size_t bytes) -> char* {
        char* p = ws + off;
        off = (off + bytes + 255) & ~(size_t)255;
        return p;
    };
    float* dinv  = (float*)alloc((size_t)N_NODES * 4);        // deg -> dinv in place
    float* enorm = (float*)alloc((size_t)N_EDGES * 4);
    int*   row   = (int*)alloc((size_t)(N_NODES + 1) * 4);
    int*   pos   = (int*)alloc((size_t)N_NODES * 4);          // count -> cursor
    int*   csrc  = (int*)alloc((size_t)N_EDGES * 4);
    float* cw    = (float*)alloc((size_t)N_EDGES * 4);
    float* ha    = (float*)alloc((size_t)N_NODES * F * 4);
    float* hb    = (float*)alloc((size_t)N_NODES * F * 4);
    float* sbuf  = ha;  // reuse after final gemm input no longer needed

    dim3 b256(256);
    int gN = (N_NODES + 255) / 256;
    int gE = (N_EDGES + 255) / 256;
    int gW = (N_NODES + 3) / 4;    // wave-per-node
    int gG = (N_NODES + 127) / 128;

    hipLaunchKernelGGL(k_fill_deg, dim3(gN), b256, 0, stream, dinv, N_NODES);
    hipLaunchKernelGGL(k_zero_int, dim3(gN), b256, 0, stream, pos, N_NODES);
    hipLaunchKernelGGL(k_deg_accum, dim3(gE), b256, 0, stream, ei, ew, dinv, N_EDGES);
    hipLaunchKernelGGL(k_dinv, dim3(gN), b256, 0, stream, dinv, N_NODES);
    hipLaunchKernelGGL(k_enorm_hist, dim3(gE), b256, 0, stream, ei, ew, dinv, enorm, pos, N_EDGES);
    hipLaunchKernelGGL(k_scan, dim3(1), dim3(1024), 0, stream, pos, row, N_NODES);
    hipLaunchKernelGGL(k_scatter, dim3(gE), b256, 0, stream, ei, enorm, pos, csrc, cw, N_EDGES);

    // layer 1: h = relu(agg(x @ W_in) + b_in)
    hipLaunchKernelGGL(k_gemm, dim3(gG), b256, 0, stream, x, Win, ha, N_NODES);
    hipLaunchKernelGGL(k_agg, dim3(gW), b256, 0, stream, ha, row, csrc, cw, dinv, bin, hb, N_NODES, 1);
    // layer 2
    hipLaunchKernelGGL(k_gemm, dim3(gG), b256, 0, stream, hb, Wmid, ha, N_NODES);
    hipLaunchKernelGGL(k_agg, dim3(gW), b256, 0, stream, ha, row, csrc, cw, dinv, bmid, hb, N_NODES, 1);
    // layer 3
    hipLaunchKernelGGL(k_gemm, dim3(gG), b256, 0, stream, hb, Wmid, ha, N_NODES);
    hipLaunchKernelGGL(k_agg, dim3(gW), b256, 0, stream, ha, row, csrc, cw, dinv, bmid, hb, N_NODES, 1);
    // final: s = h @ W_fin (128->1), then scalar aggregation + b_fin
    hipLaunchKernelGGL(k_dot, dim3(gW), b256, 0, stream, hb, Wfin, sbuf, N_NODES);
    hipLaunchKernelGGL(k_aggs, dim3(gN), b256, 0, stream, sbuf, row, csrc, cw, dinv, bfin, out, N_NODES);
}

// Round 2
// 1080.001 us; speedup vs baseline: 1.2020x; 1.2020x over previous
//
#include <hip/hip_runtime.h>
#include <stdint.h>

#define N_NODES 100000
#define N_EDGES 1600000
#define F 128

// ---------------- preprocessing kernels ----------------

__global__ void k_fill_deg(float* deg, int n) {
    int i = blockIdx.x * blockDim.x + threadIdx.x;
    if (i < n) deg[i] = 1.0f;  // implicit self-loop weight
}

__global__ void k_zero_int(int* p, int n) {
    int i = blockIdx.x * blockDim.x + threadIdx.x;
    if (i < n) p[i] = 0;
}

__global__ void k_deg_accum(const int* __restrict__ ei, const float* __restrict__ w,
                            float* deg, int e) {
    int i = blockIdx.x * blockDim.x + threadIdx.x;
    if (i < e) {
        int d = ei[N_EDGES + i];
        atomicAdd(&deg[d], w[i]);
    }
}

__global__ void k_dinv(float* deg, int n) {
    int i = blockIdx.x * blockDim.x + threadIdx.x;
    if (i < n) deg[i] = rsqrtf(deg[i]);
}

__global__ void k_enorm_hist(const int* __restrict__ ei, const float* __restrict__ w,
                             const float* __restrict__ dinv, float* enorm, int* cnt, int e) {
    int i = blockIdx.x * blockDim.x + threadIdx.x;
    if (i < e) {
        int s = ei[i];
        int d = ei[N_EDGES + i];
        enorm[i] = dinv[s] * w[i] * dinv[d];
        atomicAdd(&cnt[d], 1);
    }
}

// ---------------- hierarchical exclusive scan (3 kernels) ----------------
// phase 1: per-block sums over 1024-elem chunks
__launch_bounds__(256)
__global__ void k_bsum(const int* __restrict__ cnt, int* __restrict__ bsum, int n) {
    int b = blockIdx.x, tid = threadIdx.x;
    int base = b * 1024 + tid * 4;
    int s = 0;
#pragma unroll
    for (int j = 0; j < 4; j++)
        if (base + j < n) s += cnt[base + j];
    for (int off = 32; off; off >>= 1) s += __shfl_down(s, off, 64);
    __shared__ int ws[4];
    if ((tid & 63) == 0) ws[tid >> 6] = s;
    __syncthreads();
    if (tid == 0) bsum[b] = ws[0] + ws[1] + ws[2] + ws[3];
}

// phase 2: single small block scans the block sums (exclusive, in place)
__launch_bounds__(128)
__global__ void k_bscan(int* bsum, int nb, int* row_last) {
    __shared__ int ls[128];
    int tid = threadIdx.x;
    int v = (tid < nb) ? bsum[tid] : 0;
    ls[tid] = v;
    __syncthreads();
    for (int off = 1; off < 128; off <<= 1) {
        int t = (tid >= off) ? ls[tid - off] : 0;
        __syncthreads();
        ls[tid] += t;
        __syncthreads();
    }
    int ex = tid ? ls[tid - 1] : 0;
    if (tid < nb) bsum[tid] = ex;
    if (tid == 0) *row_last = N_EDGES;  // total count == E by construction
}

// phase 3: block-local exclusive scan + offset; writes row + pos (scatter cursor)
__launch_bounds__(256)
__global__ void k_scan2(int* __restrict__ cnt_pos, const int* __restrict__ boff,
                        int* __restrict__ row, int n) {
    __shared__ int ls[256];
    int b = blockIdx.x, tid = threadIdx.x;
    int base = b * 1024 + tid * 4;
    int v[4];
    int s = 0;
#pragma unroll
    for (int j = 0; j < 4; j++) {
        v[j] = (base + j < n) ? cnt_pos[base + j] : 0;
        s += v[j];
    }
    ls[tid] = s;
    __syncthreads();
    for (int off = 1; off < 256; off <<= 1) {
        int t = (tid >= off) ? ls[tid - off] : 0;
        __syncthreads();
        ls[tid] += t;
        __syncthreads();
    }
    int run = boff[b] + (tid ? ls[tid - 1] : 0);
#pragma unroll
    for (int j = 0; j < 4; j++) {
        if (base + j < n) {
            row[base + j] = run;
            cnt_pos[base + j] = run;  // pos copy
            run += v[j];
        }
    }
}

__global__ void k_scatter(const int* __restrict__ ei, const float* __restrict__ enorm,
                          int* pos, int* csrc, float* cw, int e) {
    int i = blockIdx.x * blockDim.x + threadIdx.x;
    if (i < e) {
        int d = ei[N_EDGES + i];
        int p = atomicAdd(&pos[d], 1);
        csrc[p] = ei[i];
        cw[p] = enorm[i];
    }
}

// ---------------- fp32 GEMM: H[nrows x 128] = X[nrows x 128] @ W[128 x 128] ----------------

#define GKT 16
#define GS 132  // padded LDS stride

__launch_bounds__(256, 4)
__global__ void k_gemm(const float* __restrict__ X, const float* __restrict__ W,
                       float* __restrict__ H, int nrows) {
    __shared__ float As[GKT * GS];  // A^T tile: As[kk][r]
    __shared__ float Bs[GKT * GS];  // B tile:  Bs[kk][c]
    int tid = threadIdx.x;
    int tx = tid & 15, ty = tid >> 4;
    int r0 = blockIdx.x * 128;
    float acc[8][8];
#pragma unroll
    for (int i = 0; i < 8; i++)
#pragma unroll
        for (int j = 0; j < 8; j++) acc[i][j] = 0.f;

    for (int k0 = 0; k0 < F; k0 += GKT) {
        // stage A (128 rows x 16 k), transposed into LDS
#pragma unroll
        for (int it = 0; it < 2; it++) {
            int f = tid + it * 256;          // 512 float4s
            int r = f >> 2;
            int kc = (f & 3) * 4;
            float4 v = make_float4(0.f, 0.f, 0.f, 0.f);
            if (r0 + r < nrows)
                v = *(const float4*)&X[(size_t)(r0 + r) * F + k0 + kc];
            As[(kc + 0) * GS + r] = v.x;
            As[(kc + 1) * GS + r] = v.y;
            As[(kc + 2) * GS + r] = v.z;
            As[(kc + 3) * GS + r] = v.w;
        }
        // stage B (16 k x 128 cols)
#pragma unroll
        for (int it = 0; it < 2; it++) {
            int f = tid + it * 256;
            int kk = f >> 5;
            int cc = (f & 31) * 4;
            *(float4*)&Bs[kk * GS + cc] = *(const float4*)&W[(size_t)(k0 + kk) * F + cc];
        }
        __syncthreads();
#pragma unroll
        for (int kk = 0; kk < GKT; kk++) {
            float a[8], b[8];
            *(float4*)&a[0] = *(const float4*)&As[kk * GS + ty * 8];
            *(float4*)&a[4] = *(const float4*)&As[kk * GS + ty * 8 + 4];
            *(float4*)&b[0] = *(const float4*)&Bs[kk * GS + tx * 8];
            *(float4*)&b[4] = *(const float4*)&Bs[kk * GS + tx * 8 + 4];
#pragma unroll
            for (int i = 0; i < 8; i++)
#pragma unroll
                for (int j = 0; j < 8; j++)
                    acc[i][j] = fmaf(a[i], b[j], acc[i][j]);
        }
        __syncthreads();
    }
#pragma unroll
    for (int i = 0; i < 8; i++) {
        int r = r0 + ty * 8 + i;
        if (r < nrows) {
            *(float4*)&H[(size_t)r * F + tx * 8] = *(float4*)&acc[i][0];
            *(float4*)&H[(size_t)r * F + tx * 8 + 4] = *(float4*)&acc[i][4];
        }
    }
}

// ---------------- aggregation: out[i] = sum_e w_e * H[src_e] + self*H[i] + b ----------------
// one wave (64 lanes) per node, 2 floats per lane

__launch_bounds__(256)
__global__ void k_agg(const float* __restrict__ H, const int* __restrict__ row,
                      const int* __restrict__ csrc, const float* __restrict__ cw,
                      const float* __restrict__ dinv, const float* __restrict__ bias,
                      float* __restrict__ out, int n, int relu) {
    int node = blockIdx.x * 4 + (threadIdx.x >> 6);
    int lane = threadIdx.x & 63;
    if (node >= n) return;
    float di = dinv[node];
    float sn = di * di;
    float2 h = *(const float2*)&H[(size_t)node * F + lane * 2];
    float2 acc;
    acc.x = sn * h.x;
    acc.y = sn * h.y;
    int beg = row[node], end = row[node + 1];
    for (int j = beg; j < end; j++) {
        int s = csrc[j];
        float w = cw[j];
        float2 v = *(const float2*)&H[(size_t)s * F + lane * 2];
        acc.x = fmaf(w, v.x, acc.x);
        acc.y = fmaf(w, v.y, acc.y);
    }
    float2 b = *(const float2*)&bias[lane * 2];
    acc.x += b.x;
    acc.y += b.y;
    if (relu) {
        acc.x = fmaxf(acc.x, 0.f);
        acc.y = fmaxf(acc.y, 0.f);
    }
    *(float2*)&out[(size_t)node * F + lane * 2] = acc;
}

// ---------------- final layer: per-node dot with W_fin, then scalar aggregation ----------------

__launch_bounds__(256)
__global__ void k_dot(const float* __restrict__ H, const float* __restrict__ Wf,
                      float* __restrict__ s, int n) {
    int node = blockIdx.x * 4 + (threadIdx.x >> 6);
    int lane = threadIdx.x & 63;
    if (node >= n) return;
    float2 h = *(const float2*)&H[(size_t)node * F + lane * 2];
    float2 w = *(const float2*)&Wf[lane * 2];
    float p = h.x * w.x + h.y * w.y;
    for (int off = 32; off; off >>= 1) p += __shfl_down(p, off, 64);
    if (lane == 0) s[node] = p;
}

__global__ void k_aggs(const float* __restrict__ s, const int* __restrict__ row,
                       const int* __restrict__ csrc, const float* __restrict__ cw,
                       const float* __restrict__ dinv, const float* __restrict__ bf,
                       float* __restrict__ out, int n) {
    int i = blockIdx.x * blockDim.x + threadIdx.x;
    if (i >= n) return;
    float di = dinv[i];
    float acc = di * di * s[i];
    int beg = row[i], end = row[i + 1];
    for (int j = beg; j < end; j++) acc = fmaf(cw[j], s[csrc[j]], acc);
    out[i] = acc + bf[0];
}

// ---------------- host launch ----------------

extern "C" void kernel_launch(void* const* d_in, const int* in_sizes, int n_in,
                              void* d_out, int out_size, void* d_ws, size_t ws_size,
                              hipStream_t stream) {
    const float* x    = (const float*)d_in[0];
    const int*   ei   = (const int*)d_in[1];   // int32 per JAX default (x64 disabled)
    const float* ew   = (const float*)d_in[2];
    const float* Win  = (const float*)d_in[3];
    const float* bin  = (const float*)d_in[4];
    const float* Wmid = (const float*)d_in[5];
    const float* bmid = (const float*)d_in[6];
    const float* Wfin = (const float*)d_in[7];
    const float* bfin = (const float*)d_in[8];
    float* out = (float*)d_out;

    char* ws = (char*)d_ws;
    size_t off = 0;
    auto alloc = [&](size_t bytes) -> char* {
        char* p = ws + off;
        off = (off + bytes + 255) & ~(size_t)255;
        return p;
    };
    float* dinv  = (float*)alloc((size_t)N_NODES * 4);        // deg -> dinv in place
    float* enorm = (float*)alloc((size_t)N_EDGES * 4);
    int*   row   = (int*)alloc((size_t)(N_NODES + 1) * 4);
    int*   pos   = (int*)alloc((size_t)N_NODES * 4);          // count -> cursor
    int*   csrc  = (int*)alloc((size_t)N_EDGES * 4);
    float* cw    = (float*)alloc((size_t)N_EDGES * 4);
    int*   bsum  = (int*)alloc(128 * 4);                      // block sums for scan
    float* ha    = (float*)alloc((size_t)N_NODES * F * 4);
    float* hb    = (float*)alloc((size_t)N_NODES * F * 4);
    float* sbuf  = ha;  // reuse after final gemm input no longer needed

    dim3 b256(256);
    int gN = (N_NODES + 255) / 256;
    int gE = (N_EDGES + 255) / 256;
    int gW = (N_NODES + 3) / 4;    // wave-per-node
    int gG = (N_NODES + 127) / 128;
    int gS = (N_NODES + 1023) / 1024;  // scan chunks (98)

    hipLaunchKernelGGL(k_fill_deg, dim3(gN), b256, 0, stream, dinv, N_NODES);
    hipLaunchKernelGGL(k_zero_int, dim3(gN), b256, 0, stream, pos, N_NODES);
    hipLaunchKernelGGL(k_deg_accum, dim3(gE), b256, 0, stream, ei, ew, dinv, N_EDGES);
    hipLaunchKernelGGL(k_dinv, dim3(gN), b256, 0, stream, dinv, N_NODES);
    hipLaunchKernelGGL(k_enorm_hist, dim3(gE), b256, 0, stream, ei, ew, dinv, enorm, pos, N_EDGES);
    // hierarchical exclusive scan of pos -> row (+ pos as scatter cursor)
    hipLaunchKernelGGL(k_bsum, dim3(gS), b256, 0, stream, pos, bsum, N_NODES);
    hipLaunchKernelGGL(k_bscan, dim3(1), dim3(128), 0, stream, bsum, gS, &row[N_NODES]);
    hipLaunchKernelGGL(k_scan2, dim3(gS), b256, 0, stream, pos, bsum, row, N_NODES);
    hipLaunchKernelGGL(k_scatter, dim3(gE), b256, 0, stream, ei, enorm, pos, csrc, cw, N_EDGES);

    // layer 1: h = relu(agg(x @ W_in) + b_in)
    hipLaunchKernelGGL(k_gemm, dim3(gG), b256, 0, stream, x, Win, ha, N_NODES);
    hipLaunchKernelGGL(k_agg, dim3(gW), b256, 0, stream, ha, row, csrc, cw, dinv, bin, hb, N_NODES, 1);
    // layer 2
    hipLaunchKernelGGL(k_gemm, dim3(gG), b256, 0, stream, hb, Wmid, ha, N_NODES);
    hipLaunchKernelGGL(k_agg, dim3(gW), b256, 0, stream, ha, row, csrc, cw, dinv, bmid, hb, N_NODES, 1);
    // layer 3
    hipLaunchKernelGGL(k_gemm, dim3(gG), b256, 0, stream, hb, Wmid, ha, N_NODES);
    hipLaunchKernelGGL(k_agg, dim3(gW), b256, 0, stream, ha, row, csrc, cw, dinv, bmid, hb, N_NODES, 1);
    // final: s = h @ W_fin (128->1), then scalar aggregation + b_fin
    hipLaunchKernelGGL(k_dot, dim3(gW), b256, 0, stream, hb, Wfin, sbuf, N_NODES);
    hipLaunchKernelGGL(k_aggs, dim3(gN), b256, 0, stream, sbuf, row, csrc, cw, dinv, bfin, out, N_NODES);
}

// Round 3
// 923.281 us; speedup vs baseline: 1.4060x; 1.1697x over previous
//
#include <hip/hip_runtime.h>
#include <stdint.h>

#define N_NODES 100000
#define N_EDGES 1600000
#define F 128

// ---------------- preprocessing kernels ----------------

__global__ void k_init(float* deg, int* cnt, int n) {
    int i = blockIdx.x * blockDim.x + threadIdx.x;
    if (i < n) { deg[i] = 1.0f; cnt[i] = 0; }  // self-loop weight 1, zero histogram
}

__global__ void k_deg_accum(const int* __restrict__ ei, const float* __restrict__ w,
                            float* deg, int e) {
    int i = blockIdx.x * blockDim.x + threadIdx.x;
    if (i < e) {
        int d = ei[N_EDGES + i];
        atomicAdd(&deg[d], w[i]);
    }
}

__global__ void k_dinv(float* deg, int n) {
    int i = blockIdx.x * blockDim.x + threadIdx.x;
    if (i < n) deg[i] = rsqrtf(deg[i]);
}

__global__ void k_enorm_hist(const int* __restrict__ ei, const float* __restrict__ w,
                             const float* __restrict__ dinv, float* enorm, int* cnt, int e) {
    int i = blockIdx.x * blockDim.x + threadIdx.x;
    if (i < e) {
        int s = ei[i];
        int d = ei[N_EDGES + i];
        enorm[i] = dinv[s] * w[i] * dinv[d];
        atomicAdd(&cnt[d], 1);
    }
}

// ---------------- hierarchical exclusive scan (3 kernels) ----------------
__launch_bounds__(256)
__global__ void k_bsum(const int* __restrict__ cnt, int* __restrict__ bsum, int n) {
    int b = blockIdx.x, tid = threadIdx.x;
    int base = b * 1024 + tid * 4;
    int s = 0;
#pragma unroll
    for (int j = 0; j < 4; j++)
        if (base + j < n) s += cnt[base + j];
    for (int off = 32; off; off >>= 1) s += __shfl_down(s, off, 64);
    __shared__ int ws[4];
    if ((tid & 63) == 0) ws[tid >> 6] = s;
    __syncthreads();
    if (tid == 0) bsum[b] = ws[0] + ws[1] + ws[2] + ws[3];
}

__launch_bounds__(128)
__global__ void k_bscan(int* bsum, int nb, int* row_last) {
    __shared__ int ls[128];
    int tid = threadIdx.x;
    int v = (tid < nb) ? bsum[tid] : 0;
    ls[tid] = v;
    __syncthreads();
    for (int off = 1; off < 128; off <<= 1) {
        int t = (tid >= off) ? ls[tid - off] : 0;
        __syncthreads();
        ls[tid] += t;
        __syncthreads();
    }
    int ex = tid ? ls[tid - 1] : 0;
    if (tid < nb) bsum[tid] = ex;
    if (tid == 0) *row_last = N_EDGES;
}

__launch_bounds__(256)
__global__ void k_scan2(int* __restrict__ cnt_pos, const int* __restrict__ boff,
                        int* __restrict__ row, int n) {
    __shared__ int ls[256];
    int b = blockIdx.x, tid = threadIdx.x;
    int base = b * 1024 + tid * 4;
    int v[4];
    int s = 0;
#pragma unroll
    for (int j = 0; j < 4; j++) {
        v[j] = (base + j < n) ? cnt_pos[base + j] : 0;
        s += v[j];
    }
    ls[tid] = s;
    __syncthreads();
    for (int off = 1; off < 256; off <<= 1) {
        int t = (tid >= off) ? ls[tid - off] : 0;
        __syncthreads();
        ls[tid] += t;
        __syncthreads();
    }
    int run = boff[b] + (tid ? ls[tid - 1] : 0);
#pragma unroll
    for (int j = 0; j < 4; j++) {
        if (base + j < n) {
            row[base + j] = run;
            cnt_pos[base + j] = run;
            run += v[j];
        }
    }
}

__global__ void k_scatter(const int* __restrict__ ei, const float* __restrict__ enorm,
                          int* pos, int* csrc, float* cw, int e) {
    int i = blockIdx.x * blockDim.x + threadIdx.x;
    if (i < e) {
        int d = ei[N_EDGES + i];
        int p = atomicAdd(&pos[d], 1);
        csrc[p] = ei[i];
        cw[p] = enorm[i];
    }
}

// ---------------- fp32 GEMM: H[nrows x 128] = X[nrows x 128] @ W[128 x 128] ----------------

#define GKT 16
#define GS 132

__launch_bounds__(256, 4)
__global__ void k_gemm(const float* __restrict__ X, const float* __restrict__ W,
                       float* __restrict__ H, int nrows) {
    __shared__ float As[GKT * GS];
    __shared__ float Bs[GKT * GS];
    int tid = threadIdx.x;
    int tx = tid & 15, ty = tid >> 4;
    int r0 = blockIdx.x * 128;
    float acc[8][8];
#pragma unroll
    for (int i = 0; i < 8; i++)
#pragma unroll
        for (int j = 0; j < 8; j++) acc[i][j] = 0.f;

    for (int k0 = 0; k0 < F; k0 += GKT) {
#pragma unroll
        for (int it = 0; it < 2; it++) {
            int f = tid + it * 256;
            int r = f >> 2;
            int kc = (f & 3) * 4;
            float4 v = make_float4(0.f, 0.f, 0.f, 0.f);
            if (r0 + r < nrows)
                v = *(const float4*)&X[(size_t)(r0 + r) * F + k0 + kc];
            As[(kc + 0) * GS + r] = v.x;
            As[(kc + 1) * GS + r] = v.y;
            As[(kc + 2) * GS + r] = v.z;
            As[(kc + 3) * GS + r] = v.w;
        }
#pragma unroll
        for (int it = 0; it < 2; it++) {
            int f = tid + it * 256;
            int kk = f >> 5;
            int cc = (f & 31) * 4;
            *(float4*)&Bs[kk * GS + cc] = *(const float4*)&W[(size_t)(k0 + kk) * F + cc];
        }
        __syncthreads();
#pragma unroll
        for (int kk = 0; kk < GKT; kk++) {
            float a[8], b[8];
            *(float4*)&a[0] = *(const float4*)&As[kk * GS + ty * 8];
            *(float4*)&a[4] = *(const float4*)&As[kk * GS + ty * 8 + 4];
            *(float4*)&b[0] = *(const float4*)&Bs[kk * GS + tx * 8];
            *(float4*)&b[4] = *(const float4*)&Bs[kk * GS + tx * 8 + 4];
#pragma unroll
            for (int i = 0; i < 8; i++)
#pragma unroll
                for (int j = 0; j < 8; j++)
                    acc[i][j] = fmaf(a[i], b[j], acc[i][j]);
        }
        __syncthreads();
    }
#pragma unroll
    for (int i = 0; i < 8; i++) {
        int r = r0 + ty * 8 + i;
        if (r < nrows) {
            *(float4*)&H[(size_t)r * F + tx * 8] = *(float4*)&acc[i][0];
            *(float4*)&H[(size_t)r * F + tx * 8 + 4] = *(float4*)&acc[i][4];
        }
    }
}

// ---------------- aggregation: out[i] = sum_e w_e * H[src_e] + self*H[i] + b ----------------
// one wave per node; lanes 0-31 = even edges, lanes 32-63 = odd edges;
// each half-wave covers a full 512B row with float4/lane; unroll x2 (4 edges in flight)

__launch_bounds__(256)
__global__ void k_agg(const float* __restrict__ H, const int* __restrict__ row,
                      const int* __restrict__ csrc, const float* __restrict__ cw,
                      const float* __restrict__ dinv, const float* __restrict__ bias,
                      float* __restrict__ out, int n, int relu) {
    int node = blockIdx.x * 4 + (threadIdx.x >> 6);
    if (node >= n) return;
    int lane = threadIdx.x & 63;
    int half = lane >> 5;
    int sub = lane & 31;
    float4 acc = make_float4(0.f, 0.f, 0.f, 0.f);
    int beg = row[node], end = row[node + 1];
    int deg = end - beg;
    int t = half;
    // unrolled: two gathers (edges t, t+2) in flight for this half-wave
    for (; t + 2 < deg; t += 4) {
        int s0 = csrc[beg + t];
        int s1 = csrc[beg + t + 2];
        float w0 = cw[beg + t];
        float w1 = cw[beg + t + 2];
        float4 v0 = *(const float4*)&H[(size_t)s0 * F + sub * 4];
        float4 v1 = *(const float4*)&H[(size_t)s1 * F + sub * 4];
        acc.x = fmaf(w0, v0.x, acc.x);
        acc.y = fmaf(w0, v0.y, acc.y);
        acc.z = fmaf(w0, v0.z, acc.z);
        acc.w = fmaf(w0, v0.w, acc.w);
        acc.x = fmaf(w1, v1.x, acc.x);
        acc.y = fmaf(w1, v1.y, acc.y);
        acc.z = fmaf(w1, v1.z, acc.z);
        acc.w = fmaf(w1, v1.w, acc.w);
    }
    for (; t < deg; t += 2) {
        int s0 = csrc[beg + t];
        float w0 = cw[beg + t];
        float4 v0 = *(const float4*)&H[(size_t)s0 * F + sub * 4];
        acc.x = fmaf(w0, v0.x, acc.x);
        acc.y = fmaf(w0, v0.y, acc.y);
        acc.z = fmaf(w0, v0.z, acc.z);
        acc.w = fmaf(w0, v0.w, acc.w);
    }
    // combine the two half-wave partials (lane i and lane i+32 hold same features)
    acc.x += __shfl_xor(acc.x, 32, 64);
    acc.y += __shfl_xor(acc.y, 32, 64);
    acc.z += __shfl_xor(acc.z, 32, 64);
    acc.w += __shfl_xor(acc.w, 32, 64);
    if (lane < 32) {
        float di = dinv[node];
        float sn = di * di;
        float4 h = *(const float4*)&H[(size_t)node * F + lane * 4];
        float4 b = *(const float4*)&bias[lane * 4];
        acc.x = fmaf(sn, h.x, acc.x) + b.x;
        acc.y = fmaf(sn, h.y, acc.y) + b.y;
        acc.z = fmaf(sn, h.z, acc.z) + b.z;
        acc.w = fmaf(sn, h.w, acc.w) + b.w;
        if (relu) {
            acc.x = fmaxf(acc.x, 0.f);
            acc.y = fmaxf(acc.y, 0.f);
            acc.z = fmaxf(acc.z, 0.f);
            acc.w = fmaxf(acc.w, 0.f);
        }
        *(float4*)&out[(size_t)node * F + lane * 4] = acc;
    }
}

// ---------------- final layer ----------------

__launch_bounds__(256)
__global__ void k_dot(const float* __restrict__ H, const float* __restrict__ Wf,
                      float* __restrict__ s, int n) {
    int node = blockIdx.x * 4 + (threadIdx.x >> 6);
    int lane = threadIdx.x & 63;
    if (node >= n) return;
    float2 h = *(const float2*)&H[(size_t)node * F + lane * 2];
    float2 w = *(const float2*)&Wf[lane * 2];
    float p = h.x * w.x + h.y * w.y;
    for (int off = 32; off; off >>= 1) p += __shfl_down(p, off, 64);
    if (lane == 0) s[node] = p;
}

__global__ void k_aggs(const float* __restrict__ s, const int* __restrict__ row,
                       const int* __restrict__ csrc, const float* __restrict__ cw,
                       const float* __restrict__ dinv, const float* __restrict__ bf,
                       float* __restrict__ out, int n) {
    int i = blockIdx.x * blockDim.x + threadIdx.x;
    if (i >= n) return;
    float di = dinv[i];
    float acc = di * di * s[i];
    int beg = row[i], end = row[i + 1];
    for (int j = beg; j < end; j++) acc = fmaf(cw[j], s[csrc[j]], acc);
    out[i] = acc + bf[0];
}

// ---------------- host launch ----------------

extern "C" void kernel_launch(void* const* d_in, const int* in_sizes, int n_in,
                              void* d_out, int out_size, void* d_ws, size_t ws_size,
                              hipStream_t stream) {
    const float* x    = (const float*)d_in[0];
    const int*   ei   = (const int*)d_in[1];
    const float* ew   = (const float*)d_in[2];
    const float* Win  = (const float*)d_in[3];
    const float* bin  = (const float*)d_in[4];
    const float* Wmid = (const float*)d_in[5];
    const float* bmid = (const float*)d_in[6];
    const float* Wfin = (const float*)d_in[7];
    const float* bfin = (const float*)d_in[8];
    float* out = (float*)d_out;

    char* ws = (char*)d_ws;
    size_t off = 0;
    auto alloc = [&](size_t bytes) -> char* {
        char* p = ws + off;
        off = (off + bytes + 255) & ~(size_t)255;
        return p;
    };
    float* dinv  = (float*)alloc((size_t)N_NODES * 4);
    float* enorm = (float*)alloc((size_t)N_EDGES * 4);
    int*   row   = (int*)alloc((size_t)(N_NODES + 1) * 4);
    int*   pos   = (int*)alloc((size_t)N_NODES * 4);
    int*   csrc  = (int*)alloc((size_t)N_EDGES * 4);
    float* cw    = (float*)alloc((size_t)N_EDGES * 4);
    int*   bsum  = (int*)alloc(128 * 4);
    float* ha    = (float*)alloc((size_t)N_NODES * F * 4);
    float* hb    = (float*)alloc((size_t)N_NODES * F * 4);
    float* sbuf  = ha;

    dim3 b256(256);
    int gN = (N_NODES + 255) / 256;
    int gE = (N_EDGES + 255) / 256;
    int gW = (N_NODES + 3) / 4;
    int gG = (N_NODES + 127) / 128;
    int gS = (N_NODES + 1023) / 1024;

    hipLaunchKernelGGL(k_init, dim3(gN), b256, 0, stream, dinv, pos, N_NODES);
    hipLaunchKernelGGL(k_deg_accum, dim3(gE), b256, 0, stream, ei, ew, dinv, N_EDGES);
    hipLaunchKernelGGL(k_dinv, dim3(gN), b256, 0, stream, dinv, N_NODES);
    hipLaunchKernelGGL(k_enorm_hist, dim3(gE), b256, 0, stream, ei, ew, dinv, enorm, pos, N_EDGES);
    hipLaunchKernelGGL(k_bsum, dim3(gS), b256, 0, stream, pos, bsum, N_NODES);
    hipLaunchKernelGGL(k_bscan, dim3(1), dim3(128), 0, stream, bsum, gS, &row[N_NODES]);
    hipLaunchKernelGGL(k_scan2, dim3(gS), b256, 0, stream, pos, bsum, row, N_NODES);
    hipLaunchKernelGGL(k_scatter, dim3(gE), b256, 0, stream, ei, enorm, pos, csrc, cw, N_EDGES);

    hipLaunchKernelGGL(k_gemm, dim3(gG), b256, 0, stream, x, Win, ha, N_NODES);
    hipLaunchKernelGGL(k_agg, dim3(gW), b256, 0, stream, ha, row, csrc, cw, dinv, bin, hb, N_NODES, 1);
    hipLaunchKernelGGL(k_gemm, dim3(gG), b256, 0, stream, hb, Wmid, ha, N_NODES);
    hipLaunchKernelGGL(k_agg, dim3(gW), b256, 0, stream, ha, row, csrc, cw, dinv, bmid, hb, N_NODES, 1);
    hipLaunchKernelGGL(k_gemm, dim3(gG), b256, 0, stream, hb, Wmid, ha, N_NODES);
    hipLaunchKernelGGL(k_agg, dim3(gW), b256, 0, stream, ha, row, csrc, cw, dinv, bmid, hb, N_NODES, 1);
    hipLaunchKernelGGL(k_dot, dim3(gW), b256, 0, stream, hb, Wfin, sbuf, N_NODES);
    hipLaunchKernelGGL(k_aggs, dim3(gN), b256, 0, stream, sbuf, row, csrc, cw, dinv, bfin, out, N_NODES);
}